// Round 8
// baseline (4028.824 us; speedup 1.0000x reference)
//
#include <hip/hip_runtime.h>
#include <hip/hip_bf16.h>
#include <math.h>

// ------------------------------------------------------------------
// CRvNN forward on MI355X. Round 8 = Round 7 + compile fix (named
// ZERO instead of braced-init-list macro args). L2-latency attack:
// 512 threads, __launch_bounds__(512,2) -> 256 VGPR budget; weight
// GEMMs use chunked batch-prefetch (16 B-frags + A-frags into
// statically indexed register arrays, one drain, then MFMAs).
// Keeps: lgkm-only barriers, atomic-free ts, LDS-resident state.
// ------------------------------------------------------------------

typedef __bf16 bf16;
typedef bf16  bf16x8 __attribute__((ext_vector_type(8)));
typedef float f32x4  __attribute__((ext_vector_type(4)));

#define MFMA16(a,b,c) __builtin_amdgcn_mfma_f32_16x16x32_bf16((a),(b),(c),0,0,0)

__device__ __forceinline__ void bar_lds() {
    asm volatile("s_waitcnt lgkmcnt(0)\n\ts_barrier" ::: "memory");
}

constexpr int LDB = 264;  // bf16 row stride for 256-wide tiles
constexpr int LDI = 520;  // bf16 row stride for 512-wide inter
constexpr int LDP = 40;   // bf16 row stride for 32x32 prob mats

// LDS arena byte offsets (total 161792 <= 163840)
constexpr int OFF_SEQ   = 0;        // f32 [32][256]  32768
constexpr int OFF_SEQB  = 32768;    // bf16 [32][264] 16896
constexpr int OFF_L1    = 49664;    // bf16 [32][264] 16896
constexpr int OFF_R1    = 66560;    // bf16 [32][264] 16896 } sTrans f32 aliases
constexpr int OFF_TMP   = 83456;    // bf16 [32][264] 16896 } R1+TMP (dead by then)
constexpr int OFF_TRANS = 66560;    // f32 [32][256]  32768 (alias)
constexpr int OFF_INTER = 100352;   // bf16 [32][520] 33280
constexpr int OFF_TMP2  = 133632;   // bf16 [32][264] 16896
constexpr int OFF_LP    = 150528;   // f32 [32][32]   4096 (consumed matvec)
constexpr int OFF_LPB   = 154624;   // bf16 [32][40]  2560
constexpr int OFF_RPB   = 157184;   // bf16 [32][40]  2560
constexpr int OFF_ACT   = 159744;   // f32 [32]
constexpr int OFF_TP    = 159872;   // f32 [32]
constexpr int OFF_IM    = 160000;   // f32 [32]
constexpr int OFF_SELP  = 160128;   // f32 [32]
constexpr int OFF_LTM   = 160256;   // f32 [32]
constexpr int OFF_ENDM  = 160384;   // f32 [32]
constexpr int OFF_REM   = 160512;   // f32 [1]
constexpr int OFF_TSP   = 160640;   // f32 [32][9] = 1152
constexpr int SMEM_BYTES = 161792;

__device__ __forceinline__ float gelu_f(float v) {
    return 0.5f * v * (1.0f + erff(v * 0.70710678118654752f));
}
__device__ __forceinline__ float sigm_f(float v) {
    return 1.0f / (1.0f + expf(-v));
}

// f32 [K][N] -> bf16 [N][K] transpose (32x32 tiles)
__global__ void transpose_bf16_kernel(const float* __restrict__ src,
                                      bf16* __restrict__ dst, int K, int N) {
    __shared__ float t[32][33];
    const int k0 = blockIdx.x * 32, n0 = blockIdx.y * 32;
    const int tx = threadIdx.x, ty = threadIdx.y;
#pragma unroll
    for (int i = 0; i < 4; ++i) {
        int k = k0 + ty + i * 8;
        t[ty + i * 8][tx] = src[(size_t)k * N + n0 + tx];
    }
    __syncthreads();
#pragma unroll
    for (int i = 0; i < 4; ++i) {
        int nn = n0 + ty + i * 8;
        dst[(size_t)nn * K + k0 + tx] = (bf16)t[tx][ty + i * 8];
    }
}

__global__ __launch_bounds__(512, 2)
void crvnn_main(const float* __restrict__ x, const float* __restrict__ inmask,
                const float* __restrict__ vSTART, const float* __restrict__ vEND,
                const float* __restrict__ b_init, const float* __restrict__ ln_g,
                const float* __restrict__ ln_b, const float* __restrict__ b_conv,
                const float* __restrict__ W_sc, const float* __restrict__ b_sc,
                const float* __restrict__ b_c1, const float* __restrict__ b_c2,
                const bf16* __restrict__ WbInit, const bf16* __restrict__ WbConv,
                const bf16* __restrict__ WbC1, const bf16* __restrict__ WbC2,
                float* __restrict__ out) {
    extern __shared__ char smem[];
    float* sSeq   = (float*)(smem + OFF_SEQ);
    bf16*  sSeqB  = (bf16*)(smem + OFF_SEQB);
    bf16*  sL1    = (bf16*)(smem + OFF_L1);
    bf16*  sR1    = (bf16*)(smem + OFF_R1);
    bf16*  sTmp   = (bf16*)(smem + OFF_TMP);
    bf16*  sTmp2  = (bf16*)(smem + OFF_TMP2);
    float* sTrans = (float*)(smem + OFF_TRANS);
    bf16*  sInter = (bf16*)(smem + OFF_INTER);
    float* sLp    = (float*)(smem + OFF_LP);
    bf16*  sLpB   = (bf16*)(smem + OFF_LPB);
    bf16*  sRpB   = (bf16*)(smem + OFF_RPB);
    float* sAct   = (float*)(smem + OFF_ACT);
    float* sTp    = (float*)(smem + OFF_TP);
    float* sIm    = (float*)(smem + OFF_IM);
    float* sSelp  = (float*)(smem + OFF_SELP);
    float* sLtm   = (float*)(smem + OFF_LTM);
    float* sEndm  = (float*)(smem + OFF_ENDM);
    float* sRem   = (float*)(smem + OFF_REM);
    float* sTsP   = (float*)(smem + OFF_TSP);   // [32][9]

    const int tid  = threadIdx.x;
    const int lane = tid & 63;
    const int w    = tid >> 6;   // wave id 0..7
    const int l15  = lane & 15;
    const int l4   = lane >> 4;  // 0..3
    const int rg   = tid >> 4;   // row 0..31 (16 threads/row)
    const int q    = tid & 15;
    const int n    = blockIdx.x; // batch

    const f32x4 ZERO = {0.f, 0.f, 0.f, 0.f};

    // ------------- masks / selp / active init -------------
    if (tid < 32) {
        const int r = tid;
        auto IM31 = [&](int j) -> float { return (j <= 0) ? 1.f : inmask[n * 30 + (j - 1)]; };
        float im_ye = (r == 0) ? 1.f : IM31(r - 1);
        float im_ne = (r <= 30) ? IM31(r) : 0.f;
        float endm  = im_ye - im_ne;
        float ins   = (r == 0) ? 0.f : im_ye;
        float ltm   = (r < 31) ? (IM31(r) - ((r <= 29) ? IM31(r + 1) : 0.f)) : 0.f;
        float selp  = ins * im_ne * (1.f - ltm);
        sIm[r] = im_ye; sEndm[r] = endm; sSelp[r] = selp; sLtm[r] = ltm; sAct[r] = im_ye;
    }
    bar_lds();

    // ------------- build seq_pre (bf16) -------------
    {
        const int r = rg;
        const float em = sEndm[r];
#pragma unroll
        for (int k = 0; k < 16; ++k) {
            int c = q + 16 * k;
            float base = (r == 0) ? vSTART[c] : ((r <= 30) ? x[(size_t)(n * 30 + (r - 1)) * 256 + c] : 0.f);
            float v = em * vEND[c] + (1.f - em) * base;
            sSeqB[r * LDB + c] = (bf16)v;
        }
    }
    bar_lds();

    // ------------- init GEMM: seq = LN(seq_pre @ W_init + b_init) * im -------------
    {
        bf16x8 bB[2][8], aA[8][2];
#pragma unroll
        for (int kt = 0; kt < 8; ++kt) {
            int kk = kt * 32 + l4 * 8;
#pragma unroll
            for (int nt = 0; nt < 2; ++nt)
                bB[nt][kt] = *(const bf16x8*)(WbInit + (size_t)(32 * w + nt * 16 + l15) * 256 + kk);
#pragma unroll
            for (int mt = 0; mt < 2; ++mt)
                aA[kt][mt] = *(const bf16x8*)(sSeqB + (mt * 16 + l15) * LDB + kk);
        }
        f32x4 acc[2][2];
#pragma unroll
        for (int mt = 0; mt < 2; ++mt)
#pragma unroll
            for (int nt = 0; nt < 2; ++nt) acc[mt][nt] = ZERO;
#pragma unroll
        for (int kt = 0; kt < 8; ++kt)
#pragma unroll
            for (int nt = 0; nt < 2; ++nt) {
                acc[0][nt] = MFMA16(aA[kt][0], bB[nt][kt], acc[0][nt]);
                acc[1][nt] = MFMA16(aA[kt][1], bB[nt][kt], acc[1][nt]);
            }
#pragma unroll
        for (int mt = 0; mt < 2; ++mt)
#pragma unroll
            for (int nt = 0; nt < 2; ++nt)
#pragma unroll
                for (int i = 0; i < 4; ++i) {
                    int row = mt * 16 + l4 * 4 + i, col = 32 * w + nt * 16 + l15;
                    sSeq[row * 256 + col] = acc[mt][nt][i] + b_init[col];
                }
    }
    bar_lds();
    {   // layernorm rows, * im
        const int r = rg;
        float s = 0.f, s2 = 0.f, vals[16];
#pragma unroll
        for (int k = 0; k < 16; ++k) {
            float v = sSeq[r * 256 + q + 16 * k];
            vals[k] = v; s += v; s2 += v * v;
        }
        for (int m = 1; m < 16; m <<= 1) { s += __shfl_xor(s, m); s2 += __shfl_xor(s2, m); }
        float mu = s * (1.f / 256.f);
        float var = s2 * (1.f / 256.f) - mu * mu;
        float rstd = rsqrtf(var + 1e-5f);
        float imr = sIm[r];
#pragma unroll
        for (int k = 0; k < 16; ++k) {
            int c = q + 16 * k;
            sSeq[r * 256 + c] = ((vals[k] - mu) * rstd * ln_g[c] + ln_b[c]) * imr;
        }
    }
    bar_lds();

    // ==================== scan: 30 steps ====================
    for (int step = 0; step < 30; ++step) {
        // ---- phase 1: neighbor probs (wave 0), seqB refresh ----
        if (tid < 32) {
            const int i = tid;
            for (int j = 0; j < 32; ++j) {
                sLp[i * 32 + j] = 0.f;
                sRpB[i * LDP + j] = (bf16)0.f; sLpB[i * LDP + j] = (bf16)0.f;
            }
            float cc = 0.f;
            for (int j = i + 1; j < 32; ++j) {
                float am = sAct[j] * sIm[j];
                float cp = cc; cc += am;
                float v = (cc > 1.f) ? fmaxf(1.f - cp, 0.f) : am;
                v *= sIm[j];
                sRpB[i * LDP + j] = (bf16)v;
            }
            cc = 0.f;
            for (int j = i - 1; j >= 0; --j) {
                float am = sAct[j] * sIm[j];
                float cp = cc; cc += am;
                float v = (cc > 1.f) ? fmaxf(1.f - cp, 0.f) : am;
                v *= sIm[j];
                sLp[i * 32 + j] = v; sLpB[i * LDP + j] = (bf16)v;
            }
            if (i == 0) {
                float rm = 0.f;
                for (int j = 0; j < 32; ++j) rm += sAct[j] * sSelp[j];
                *sRem = rm;
            }
        }
        {
            const int r = rg;
#pragma unroll
            for (int k = 0; k < 16; ++k) {
                int c = q + 16 * k;
                sSeqB[r * LDB + c] = (bf16)sSeq[r * 256 + c];
            }
        }
        bar_lds();
        if (*sRem <= 0.01f) break;  // u == 0 -> remaining steps identity (exact)

        const int n0 = 32 * w;  // this wave's 32-col slice (nt=0,1)

        // ---- phase 2: L1 = Lp@seq, R1 = Rp@seq ----
        {
            bf16x8 aL0 = *(const bf16x8*)(sLpB + l15 * LDP + l4 * 8);
            bf16x8 aL1v = *(const bf16x8*)(sLpB + (16 + l15) * LDP + l4 * 8);
            bf16x8 aR0 = *(const bf16x8*)(sRpB + l15 * LDP + l4 * 8);
            bf16x8 aR1v = *(const bf16x8*)(sRpB + (16 + l15) * LDP + l4 * 8);
            bf16x8 bx[2];
#pragma unroll
            for (int nt = 0; nt < 2; ++nt)
#pragma unroll
                for (int s2 = 0; s2 < 8; ++s2)
                    bx[nt][s2] = sSeqB[(l4 * 8 + s2) * LDB + n0 + nt * 16 + l15];
            f32x4 accL[2][2], accR[2][2];
#pragma unroll
            for (int nt = 0; nt < 2; ++nt) {
                accL[0][nt] = MFMA16(aL0, bx[nt], ZERO);
                accL[1][nt] = MFMA16(aL1v, bx[nt], ZERO);
                accR[0][nt] = MFMA16(aR0, bx[nt], ZERO);
                accR[1][nt] = MFMA16(aR1v, bx[nt], ZERO);
            }
#pragma unroll
            for (int mt = 0; mt < 2; ++mt)
#pragma unroll
                for (int nt = 0; nt < 2; ++nt)
#pragma unroll
                    for (int i = 0; i < 4; ++i) {
                        int row = mt * 16 + l4 * 4 + i, col = n0 + nt * 16 + l15;
                        sL1[row * LDB + col] = (bf16)accL[mt][nt][i];
                        sR1[row * LDB + col] = (bf16)accR[mt][nt][i];
                    }
        }
        bar_lds();

        // ---- phase 3: L2 -> sTmp ; R2 -> sTmp2 ; inter = gelu([L1,seq]@W_c1+b) ----
        {
            bf16x8 aL0 = *(const bf16x8*)(sLpB + l15 * LDP + l4 * 8);
            bf16x8 aL1v = *(const bf16x8*)(sLpB + (16 + l15) * LDP + l4 * 8);
            bf16x8 aR0 = *(const bf16x8*)(sRpB + l15 * LDP + l4 * 8);
            bf16x8 aR1v = *(const bf16x8*)(sRpB + (16 + l15) * LDP + l4 * 8);
            bf16x8 bxL[2], bxR[2];
#pragma unroll
            for (int nt = 0; nt < 2; ++nt)
#pragma unroll
                for (int s2 = 0; s2 < 8; ++s2) {
                    bxL[nt][s2] = sL1[(l4 * 8 + s2) * LDB + n0 + nt * 16 + l15];
                    bxR[nt][s2] = sR1[(l4 * 8 + s2) * LDB + n0 + nt * 16 + l15];
                }
            f32x4 acc2[2][2], acc3[2][2];
#pragma unroll
            for (int nt = 0; nt < 2; ++nt) {
                acc2[0][nt] = MFMA16(aL0, bxL[nt], ZERO);
                acc2[1][nt] = MFMA16(aL1v, bxL[nt], ZERO);
                acc3[0][nt] = MFMA16(aR0, bxR[nt], ZERO);
                acc3[1][nt] = MFMA16(aR1v, bxR[nt], ZERO);
            }
#pragma unroll
            for (int mt = 0; mt < 2; ++mt)
#pragma unroll
                for (int nt = 0; nt < 2; ++nt)
#pragma unroll
                    for (int i = 0; i < 4; ++i) {
                        int row = mt * 16 + l4 * 4 + i, col = n0 + nt * 16 + l15;
                        sTmp[row * LDB + col] = (bf16)acc2[mt][nt][i];
                        sTmp2[row * LDB + col] = (bf16)acc3[mt][nt][i];
                    }
            // c1 GEMM: 64 cols/wave, chunked by kt-quarters (16 B + 8 A per chunk)
            f32x4 c1a[2][4];
#pragma unroll
            for (int mt = 0; mt < 2; ++mt)
#pragma unroll
                for (int nt = 0; nt < 4; ++nt) c1a[mt][nt] = ZERO;
#pragma unroll
            for (int ktq = 0; ktq < 4; ++ktq) {
                const bf16* Ab = (ktq < 2) ? sL1 : sSeqB;
                bf16x8 bB[4][4], aA[4][2];
#pragma unroll
                for (int ktl = 0; ktl < 4; ++ktl) {
                    int kt = ktq * 4 + ktl;
                    int kk = (kt & 7) * 32 + l4 * 8;
#pragma unroll
                    for (int nt = 0; nt < 4; ++nt)
                        bB[ktl][nt] = *(const bf16x8*)(WbC1 + (size_t)(64 * w + nt * 16 + l15) * 512 + kt * 32 + l4 * 8);
#pragma unroll
                    for (int mt = 0; mt < 2; ++mt)
                        aA[ktl][mt] = *(const bf16x8*)(Ab + (mt * 16 + l15) * LDB + kk);
                }
#pragma unroll
                for (int ktl = 0; ktl < 4; ++ktl)
#pragma unroll
                    for (int nt = 0; nt < 4; ++nt) {
                        c1a[0][nt] = MFMA16(aA[ktl][0], bB[ktl][nt], c1a[0][nt]);
                        c1a[1][nt] = MFMA16(aA[ktl][1], bB[ktl][nt], c1a[1][nt]);
                    }
            }
#pragma unroll
            for (int mt = 0; mt < 2; ++mt)
#pragma unroll
                for (int nt = 0; nt < 4; ++nt)
#pragma unroll
                    for (int i = 0; i < 4; ++i) {
                        int row = mt * 16 + l4 * 4 + i, col = 64 * w + nt * 16 + l15;
                        float v = c1a[mt][nt][i] + b_c1[col];
                        sInter[row * LDI + col] = (bf16)gelu_f(v);
                    }
        }
        bar_lds();

        // ---- phase 4: conv over 5 slices (chunk = slice: 16 B + 16 A) + ts ----
        {
            f32x4 cva[2][2];
#pragma unroll
            for (int mt = 0; mt < 2; ++mt)
#pragma unroll
                for (int nt = 0; nt < 2; ++nt) cva[mt][nt] = ZERO;
            const bf16* slices[5] = { sTmp, sL1, sSeqB, sR1, sTmp2 };
#pragma unroll
            for (int sl = 0; sl < 5; ++sl) {
                const bf16* Ab = slices[sl];
                bf16x8 bB[8][2], aA[8][2];
#pragma unroll
                for (int kt = 0; kt < 8; ++kt) {
                    int kk = kt * 32 + l4 * 8;
#pragma unroll
                    for (int nt = 0; nt < 2; ++nt)
                        bB[kt][nt] = *(const bf16x8*)(WbConv + (size_t)(n0 + nt * 16 + l15) * 1280 + sl * 256 + kk);
#pragma unroll
                    for (int mt = 0; mt < 2; ++mt)
                        aA[kt][mt] = *(const bf16x8*)(Ab + (mt * 16 + l15) * LDB + kk);
                }
#pragma unroll
                for (int kt = 0; kt < 8; ++kt)
#pragma unroll
                    for (int nt = 0; nt < 2; ++nt) {
                        cva[0][nt] = MFMA16(aA[kt][0], bB[kt][nt], cva[0][nt]);
                        cva[1][nt] = MFMA16(aA[kt][1], bB[kt][nt], cva[1][nt]);
                    }
            }
#pragma unroll
            for (int mt = 0; mt < 2; ++mt)
#pragma unroll
                for (int i = 0; i < 4; ++i) {
                    int row = mt * 16 + l4 * 4 + i;
                    float p = 0.f;
#pragma unroll
                    for (int nt = 0; nt < 2; ++nt) {
                        int col = n0 + nt * 16 + l15;
                        float hv = gelu_f(cva[mt][nt][i] + b_conv[col]);
                        p += hv * W_sc[col];
                    }
                    p += __shfl_xor(p, 1); p += __shfl_xor(p, 2);
                    p += __shfl_xor(p, 4); p += __shfl_xor(p, 8);
                    if (l15 == 0) sTsP[row * 9 + w] = p;
                }
        }
        bar_lds();

        // ---- phase 5: tp ; c2 GEMM (chunk = g x kt-half) ; gates -> trans_pre ----
        if (tid < 32) {
            float t = b_sc[0];
#pragma unroll
            for (int ww = 0; ww < 8; ++ww) t += sTsP[tid * 9 + ww];
            sTp[tid] = sSelp[tid] * sigm_f(t);
        }
        {
            f32x4 c2a[2][2][4];
#pragma unroll
            for (int mt = 0; mt < 2; ++mt)
#pragma unroll
                for (int di = 0; di < 2; ++di)
#pragma unroll
                    for (int g = 0; g < 4; ++g) c2a[mt][di][g] = ZERO;
#pragma unroll
            for (int g = 0; g < 4; ++g)
#pragma unroll
                for (int kh = 0; kh < 2; ++kh) {
                    bf16x8 bB[8][2], aA[8][2];
#pragma unroll
                    for (int ktl = 0; ktl < 8; ++ktl) {
                        int kt = kh * 8 + ktl;
                        int kk = kt * 32 + l4 * 8;
#pragma unroll
                        for (int di = 0; di < 2; ++di) {
                            int col = g * 256 + (2 * w + di) * 16 + l15;
                            bB[ktl][di] = *(const bf16x8*)(WbC2 + (size_t)col * 512 + kk);
                        }
#pragma unroll
                        for (int mt = 0; mt < 2; ++mt)
                            aA[ktl][mt] = *(const bf16x8*)(sInter + (mt * 16 + l15) * LDI + kk);
                    }
#pragma unroll
                    for (int ktl = 0; ktl < 8; ++ktl)
#pragma unroll
                        for (int di = 0; di < 2; ++di) {
                            c2a[0][di][g] = MFMA16(aA[ktl][0], bB[ktl][di], c2a[0][di][g]);
                            c2a[1][di][g] = MFMA16(aA[ktl][1], bB[ktl][di], c2a[1][di][g]);
                        }
                }
#pragma unroll
            for (int mt = 0; mt < 2; ++mt)
#pragma unroll
                for (int di = 0; di < 2; ++di)
#pragma unroll
                    for (int i = 0; i < 4; ++i) {
                        int row = mt * 16 + l4 * 4 + i;
                        int d = (2 * w + di) * 16 + l15;
                        float c0 = c2a[mt][di][0][i] + b_c2[d];
                        float c1v = c2a[mt][di][1][i] + b_c2[256 + d];
                        float c2v = c2a[mt][di][2][i] + b_c2[512 + d];
                        float c3v = c2a[mt][di][3][i] + b_c2[768 + d];
                        float g0 = sigm_f(c0), g1 = sigm_f(c1v), g2 = sigm_f(c2v);
                        float lc = (float)sL1[row * LDB + d];
                        float sv = sSeq[row * 256 + d];
                        sTrans[row * 256 + d] = g0 * lc + g1 * sv + g2 * c3v;
                    }
        }
        bar_lds();

        // ---- phase 6: trans = LN(trans_pre); seq update; active update ----
        {
            const int r = rg;
            float s = 0.f, s2 = 0.f, vals[16];
#pragma unroll
            for (int k = 0; k < 16; ++k) {
                float v = sTrans[r * 256 + q + 16 * k];
                vals[k] = v; s += v; s2 += v * v;
            }
            for (int m = 1; m < 16; m <<= 1) { s += __shfl_xor(s, m); s2 += __shfl_xor(s2, m); }
            float mu = s * (1.f / 256.f);
            float var = s2 * (1.f / 256.f) - mu * mu;
            float rstd = rsqrtf(var + 1e-5f);
            float tpv = sTp[r], imr = sIm[r];
#pragma unroll
            for (int k = 0; k < 16; ++k) {
                int c = q + 16 * k;
                float tr = (vals[k] - mu) * rstd * ln_g[c] + ln_b[c];
                float sv = sSeq[r * 256 + c];
                sSeq[r * 256 + c] = (tpv * tr + (1.f - tpv) * sv) * imr;
            }
        }
        if (tid < 32) {
            const int j = tid;
            float cons = 0.f;
            for (int i = 0; i < 32; ++i) cons += sLp[i * 32 + j] * sTp[i];
            sAct[j] = fmaxf(sAct[j] - cons, 0.f);
        }
        bar_lds();
    }

    // ---- output: sum_j ltm[j] * seq[j] ----
    if (tid < 256) {
        float o = 0.f;
        for (int j = 0; j < 32; ++j) o += sLtm[j] * sSeq[j * 256 + tid];
        out[(size_t)n * 256 + tid] = o;
    }
}

extern "C" void kernel_launch(void* const* d_in, const int* in_sizes, int n_in,
                              void* d_out, int out_size, void* d_ws, size_t ws_size,
                              hipStream_t stream) {
    const float* x       = (const float*)d_in[0];
    const float* inmask  = (const float*)d_in[1];
    const float* vSTART  = (const float*)d_in[2];
    const float* vEND    = (const float*)d_in[3];
    const float* W_init  = (const float*)d_in[4];
    const float* b_init  = (const float*)d_in[5];
    const float* ln_g    = (const float*)d_in[6];
    const float* ln_b    = (const float*)d_in[7];
    const float* W_conv  = (const float*)d_in[8];
    const float* b_conv  = (const float*)d_in[9];
    const float* W_sc    = (const float*)d_in[10];
    const float* b_sc    = (const float*)d_in[11];
    const float* W_c1    = (const float*)d_in[12];
    const float* b_c1    = (const float*)d_in[13];
    const float* W_c2    = (const float*)d_in[14];
    const float* b_c2    = (const float*)d_in[15];
    float* out = (float*)d_out;

    bf16* WbInit = (bf16*)d_ws;                 // 256 x 256
    bf16* WbConv = WbInit + 256 * 256;          // 256 x 1280
    bf16* WbC1   = WbConv + 256 * 1280;         // 512 x 512
    bf16* WbC2   = WbC1 + 512 * 512;            // 1024 x 512

    dim3 tb(32, 8);
    transpose_bf16_kernel<<<dim3(256 / 32, 256 / 32), tb, 0, stream>>>(W_init, WbInit, 256, 256);
    transpose_bf16_kernel<<<dim3(1280 / 32, 256 / 32), tb, 0, stream>>>(W_conv, WbConv, 1280, 256);
    transpose_bf16_kernel<<<dim3(512 / 32, 512 / 32), tb, 0, stream>>>(W_c1, WbC1, 512, 512);
    transpose_bf16_kernel<<<dim3(512 / 32, 1024 / 32), tb, 0, stream>>>(W_c2, WbC2, 512, 1024);

    (void)hipFuncSetAttribute((const void*)crvnn_main,
                              hipFuncAttributeMaxDynamicSharedMemorySize, SMEM_BYTES);
    crvnn_main<<<dim3(16), dim3(512), SMEM_BYTES, stream>>>(
        x, inmask, vSTART, vEND, b_init, ln_g, ln_b, b_conv, W_sc, b_sc,
        b_c1, b_c2, WbInit, WbConv, WbC1, WbC2, out);
}

// Round 9
// 3314.437 us; speedup vs baseline: 1.2155x; 1.2155x over previous
//
#include <hip/hip_runtime.h>
#include <hip/hip_bf16.h>
#include <math.h>

// ------------------------------------------------------------------
// CRvNN forward on MI355X. Round 9: I-cache attack. All big GEMMs go
// through ONE noinline rolled-loop tile function (gtile) so the hot
// step body shrinks from ~40-60KB to ~10KB (< 32KB L1I). Acc passed
// by value (stays in VGPRs). Config otherwise = R4/R6: 512 thr,
// 16 blocks, LDS-resident state, lgkm-only barriers, atomic-free ts.
// ------------------------------------------------------------------

typedef __bf16 bf16;
typedef bf16  bf16x8 __attribute__((ext_vector_type(8)));
typedef float f32x4  __attribute__((ext_vector_type(4)));

#define MFMA16(a,b,c) __builtin_amdgcn_mfma_f32_16x16x32_bf16((a),(b),(c),0,0,0)

__device__ __forceinline__ void bar_lds() {
    asm volatile("s_waitcnt lgkmcnt(0)\n\ts_barrier" ::: "memory");
}

constexpr int LDB = 264;  // bf16 row stride for 256-wide tiles
constexpr int LDI = 520;  // bf16 row stride for 512-wide inter
constexpr int LDP = 40;   // bf16 row stride for 32x32 prob mats

// LDS arena byte offsets (total 161792 <= 163840)
constexpr int OFF_SEQ   = 0;        // f32 [32][256]  32768
constexpr int OFF_SEQB  = 32768;    // bf16 [32][264] 16896
constexpr int OFF_L1    = 49664;    // bf16 [32][264] 16896
constexpr int OFF_R1    = 66560;    // bf16 [32][264] 16896 } sTrans f32 aliases
constexpr int OFF_TMP   = 83456;    // bf16 [32][264] 16896 } R1+TMP (dead by then)
constexpr int OFF_TRANS = 66560;    // f32 [32][256]  32768 (alias)
constexpr int OFF_INTER = 100352;   // bf16 [32][520] 33280
constexpr int OFF_TMP2  = 133632;   // bf16 [32][264] 16896
constexpr int OFF_LP    = 150528;   // f32 [32][32]   4096 (consumed matvec)
constexpr int OFF_LPB   = 154624;   // bf16 [32][40]  2560
constexpr int OFF_RPB   = 157184;   // bf16 [32][40]  2560
constexpr int OFF_ACT   = 159744;   // f32 [32]
constexpr int OFF_TP    = 159872;   // f32 [32]
constexpr int OFF_IM    = 160000;   // f32 [32]
constexpr int OFF_SELP  = 160128;   // f32 [32]
constexpr int OFF_LTM   = 160256;   // f32 [32]
constexpr int OFF_ENDM  = 160384;   // f32 [32]
constexpr int OFF_REM   = 160512;   // f32 [1]
constexpr int OFF_TSP   = 160640;   // f32 [32][9] = 1152
constexpr int SMEM_BYTES = 161792;

__device__ __forceinline__ float gelu_f(float v) {
    return 0.5f * v * (1.0f + erff(v * 0.70710678118654752f));
}
__device__ __forceinline__ float sigm_f(float v) {
    return 1.0f / (1.0f + expf(-v));
}

struct Acc2 { f32x4 a0, a1; };

// One 32-row x 16-col MFMA tile, K = 32*nkt, A from LDS, W (pre-offset
// to this tile's column base) from global. Rolled loop on purpose:
// this is THE hot GEMM code, shared by init/c1/conv/c2 -> tiny I-cache
// footprint. noinline so call sites don't re-expand it.
__device__ __attribute__((noinline))
Acc2 gtile(const bf16* __restrict__ A, int ldA,
           const bf16* __restrict__ W, int ldW, int nkt, Acc2 acc) {
    const int lane = threadIdx.x & 63;
    const int l15 = lane & 15;
    const int l4  = lane >> 4;
    const bf16* Wp = W + (size_t)l15 * ldW + l4 * 8;
    const bf16* Ap0 = A + l15 * ldA + l4 * 8;
    const bf16* Ap1 = A + (16 + l15) * ldA + l4 * 8;
    for (int k = 0; k < nkt; ++k) {
        bf16x8 b  = *(const bf16x8*)(Wp + k * 32);
        bf16x8 a0 = *(const bf16x8*)(Ap0 + k * 32);
        bf16x8 a1 = *(const bf16x8*)(Ap1 + k * 32);
        acc.a0 = MFMA16(a0, b, acc.a0);
        acc.a1 = MFMA16(a1, b, acc.a1);
    }
    return acc;
}

// f32 [K][N] -> bf16 [N][K] transpose (32x32 tiles)
__global__ void transpose_bf16_kernel(const float* __restrict__ src,
                                      bf16* __restrict__ dst, int K, int N) {
    __shared__ float t[32][33];
    const int k0 = blockIdx.x * 32, n0 = blockIdx.y * 32;
    const int tx = threadIdx.x, ty = threadIdx.y;
#pragma unroll
    for (int i = 0; i < 4; ++i) {
        int k = k0 + ty + i * 8;
        t[ty + i * 8][tx] = src[(size_t)k * N + n0 + tx];
    }
    __syncthreads();
#pragma unroll
    for (int i = 0; i < 4; ++i) {
        int nn = n0 + ty + i * 8;
        dst[(size_t)nn * K + k0 + tx] = (bf16)t[tx][ty + i * 8];
    }
}

__global__ __launch_bounds__(512, 2)
void crvnn_main(const float* __restrict__ x, const float* __restrict__ inmask,
                const float* __restrict__ vSTART, const float* __restrict__ vEND,
                const float* __restrict__ b_init, const float* __restrict__ ln_g,
                const float* __restrict__ ln_b, const float* __restrict__ b_conv,
                const float* __restrict__ W_sc, const float* __restrict__ b_sc,
                const float* __restrict__ b_c1, const float* __restrict__ b_c2,
                const bf16* __restrict__ WbInit, const bf16* __restrict__ WbConv,
                const bf16* __restrict__ WbC1, const bf16* __restrict__ WbC2,
                float* __restrict__ out) {
    extern __shared__ char smem[];
    float* sSeq   = (float*)(smem + OFF_SEQ);
    bf16*  sSeqB  = (bf16*)(smem + OFF_SEQB);
    bf16*  sL1    = (bf16*)(smem + OFF_L1);
    bf16*  sR1    = (bf16*)(smem + OFF_R1);
    bf16*  sTmp   = (bf16*)(smem + OFF_TMP);
    bf16*  sTmp2  = (bf16*)(smem + OFF_TMP2);
    float* sTrans = (float*)(smem + OFF_TRANS);
    bf16*  sInter = (bf16*)(smem + OFF_INTER);
    float* sLp    = (float*)(smem + OFF_LP);
    bf16*  sLpB   = (bf16*)(smem + OFF_LPB);
    bf16*  sRpB   = (bf16*)(smem + OFF_RPB);
    float* sAct   = (float*)(smem + OFF_ACT);
    float* sTp    = (float*)(smem + OFF_TP);
    float* sIm    = (float*)(smem + OFF_IM);
    float* sSelp  = (float*)(smem + OFF_SELP);
    float* sLtm   = (float*)(smem + OFF_LTM);
    float* sEndm  = (float*)(smem + OFF_ENDM);
    float* sRem   = (float*)(smem + OFF_REM);
    float* sTsP   = (float*)(smem + OFF_TSP);   // [32][9]

    const int tid  = threadIdx.x;
    const int lane = tid & 63;
    const int w    = tid >> 6;   // wave id 0..7
    const int l15  = lane & 15;
    const int l4   = lane >> 4;  // 0..3
    const int rg   = tid >> 4;   // row 0..31 (16 threads/row)
    const int q    = tid & 15;
    const int n    = blockIdx.x; // batch

    const f32x4 ZEROV = {0.f, 0.f, 0.f, 0.f};
    const Acc2 ZACC = { ZEROV, ZEROV };

    // ------------- masks / selp / active init -------------
    if (tid < 32) {
        const int r = tid;
        auto IM31 = [&](int j) -> float { return (j <= 0) ? 1.f : inmask[n * 30 + (j - 1)]; };
        float im_ye = (r == 0) ? 1.f : IM31(r - 1);
        float im_ne = (r <= 30) ? IM31(r) : 0.f;
        float endm  = im_ye - im_ne;
        float ins   = (r == 0) ? 0.f : im_ye;
        float ltm   = (r < 31) ? (IM31(r) - ((r <= 29) ? IM31(r + 1) : 0.f)) : 0.f;
        float selp  = ins * im_ne * (1.f - ltm);
        sIm[r] = im_ye; sEndm[r] = endm; sSelp[r] = selp; sLtm[r] = ltm; sAct[r] = im_ye;
    }
    bar_lds();

    // ------------- build seq_pre (bf16) -------------
    {
        const int r = rg;
        const float em = sEndm[r];
        for (int k = 0; k < 16; ++k) {
            int c = q + 16 * k;
            float base = (r == 0) ? vSTART[c] : ((r <= 30) ? x[(size_t)(n * 30 + (r - 1)) * 256 + c] : 0.f);
            float v = em * vEND[c] + (1.f - em) * base;
            sSeqB[r * LDB + c] = (bf16)v;
        }
    }
    bar_lds();

    // ------------- init GEMM: seq = LN(seq_pre @ W_init + b_init) * im -------------
    for (int nt = 0; nt < 2; ++nt) {
        Acc2 a = gtile(sSeqB, LDB, WbInit + (size_t)(32 * w + nt * 16) * 256, 256, 8, ZACC);
        const int col = 32 * w + nt * 16 + l15;
        const float bi = b_init[col];
#pragma unroll
        for (int i = 0; i < 4; ++i) {
            sSeq[(l4 * 4 + i) * 256 + col] = a.a0[i] + bi;
            sSeq[(16 + l4 * 4 + i) * 256 + col] = a.a1[i] + bi;
        }
    }
    bar_lds();
    {   // layernorm rows, * im
        const int r = rg;
        float s = 0.f, s2 = 0.f, vals[16];
        for (int k = 0; k < 16; ++k) {
            float v = sSeq[r * 256 + q + 16 * k];
            vals[k] = v; s += v; s2 += v * v;
        }
        for (int m = 1; m < 16; m <<= 1) { s += __shfl_xor(s, m); s2 += __shfl_xor(s2, m); }
        float mu = s * (1.f / 256.f);
        float var = s2 * (1.f / 256.f) - mu * mu;
        float rstd = rsqrtf(var + 1e-5f);
        float imr = sIm[r];
        for (int k = 0; k < 16; ++k) {
            int c = q + 16 * k;
            sSeq[r * 256 + c] = ((vals[k] - mu) * rstd * ln_g[c] + ln_b[c]) * imr;
        }
    }
    bar_lds();

    // ==================== scan: 30 steps ====================
    for (int step = 0; step < 30; ++step) {
        // ---- phase 1: neighbor probs (wave 0), seqB refresh ----
        if (tid < 32) {
            const int i = tid;
            for (int j = 0; j < 32; ++j) {
                sLp[i * 32 + j] = 0.f;
                sRpB[i * LDP + j] = (bf16)0.f; sLpB[i * LDP + j] = (bf16)0.f;
            }
            float cc = 0.f;
            for (int j = i + 1; j < 32; ++j) {
                float am = sAct[j] * sIm[j];
                float cp = cc; cc += am;
                float v = (cc > 1.f) ? fmaxf(1.f - cp, 0.f) : am;
                v *= sIm[j];
                sRpB[i * LDP + j] = (bf16)v;
            }
            cc = 0.f;
            for (int j = i - 1; j >= 0; --j) {
                float am = sAct[j] * sIm[j];
                float cp = cc; cc += am;
                float v = (cc > 1.f) ? fmaxf(1.f - cp, 0.f) : am;
                v *= sIm[j];
                sLp[i * 32 + j] = v; sLpB[i * LDP + j] = (bf16)v;
            }
            if (i == 0) {
                float rm = 0.f;
                for (int j = 0; j < 32; ++j) rm += sAct[j] * sSelp[j];
                *sRem = rm;
            }
        }
        {
            const int r = rg;
            for (int k = 0; k < 16; ++k) {
                int c = q + 16 * k;
                sSeqB[r * LDB + c] = (bf16)sSeq[r * 256 + c];
            }
        }
        bar_lds();
        if (*sRem <= 0.01f) break;  // u == 0 -> remaining steps identity (exact)

        const int n0 = 32 * w;  // this wave's 32-col slice (nt=0,1)

        // ---- phase 2: L1 = Lp@seq, R1 = Rp@seq ----
        {
            bf16x8 aL0 = *(const bf16x8*)(sLpB + l15 * LDP + l4 * 8);
            bf16x8 aL1v = *(const bf16x8*)(sLpB + (16 + l15) * LDP + l4 * 8);
            bf16x8 aR0 = *(const bf16x8*)(sRpB + l15 * LDP + l4 * 8);
            bf16x8 aR1v = *(const bf16x8*)(sRpB + (16 + l15) * LDP + l4 * 8);
            for (int nt = 0; nt < 2; ++nt) {
                const int col = n0 + nt * 16 + l15;
                bf16x8 bx;
                for (int s2 = 0; s2 < 8; ++s2) bx[s2] = sSeqB[(l4 * 8 + s2) * LDB + col];
                f32x4 aL_0 = MFMA16(aL0, bx, ZEROV);
                f32x4 aL_1 = MFMA16(aL1v, bx, ZEROV);
                f32x4 aR_0 = MFMA16(aR0, bx, ZEROV);
                f32x4 aR_1 = MFMA16(aR1v, bx, ZEROV);
#pragma unroll
                for (int i = 0; i < 4; ++i) {
                    sL1[(l4 * 4 + i) * LDB + col] = (bf16)aL_0[i];
                    sL1[(16 + l4 * 4 + i) * LDB + col] = (bf16)aL_1[i];
                    sR1[(l4 * 4 + i) * LDB + col] = (bf16)aR_0[i];
                    sR1[(16 + l4 * 4 + i) * LDB + col] = (bf16)aR_1[i];
                }
            }
        }
        bar_lds();

        // ---- phase 3: L2 -> sTmp ; R2 -> sTmp2 ; inter = gelu([L1,seq]@W_c1+b) ----
        {
            bf16x8 aL0 = *(const bf16x8*)(sLpB + l15 * LDP + l4 * 8);
            bf16x8 aL1v = *(const bf16x8*)(sLpB + (16 + l15) * LDP + l4 * 8);
            bf16x8 aR0 = *(const bf16x8*)(sRpB + l15 * LDP + l4 * 8);
            bf16x8 aR1v = *(const bf16x8*)(sRpB + (16 + l15) * LDP + l4 * 8);
            for (int nt = 0; nt < 2; ++nt) {
                const int col = n0 + nt * 16 + l15;
                bf16x8 bxL, bxR;
                for (int s2 = 0; s2 < 8; ++s2) {
                    bxL[s2] = sL1[(l4 * 8 + s2) * LDB + col];
                    bxR[s2] = sR1[(l4 * 8 + s2) * LDB + col];
                }
                f32x4 t0 = MFMA16(aL0, bxL, ZEROV);
                f32x4 t1 = MFMA16(aL1v, bxL, ZEROV);
                f32x4 u0 = MFMA16(aR0, bxR, ZEROV);
                f32x4 u1 = MFMA16(aR1v, bxR, ZEROV);
#pragma unroll
                for (int i = 0; i < 4; ++i) {
                    sTmp[(l4 * 4 + i) * LDB + col] = (bf16)t0[i];
                    sTmp[(16 + l4 * 4 + i) * LDB + col] = (bf16)t1[i];
                    sTmp2[(l4 * 4 + i) * LDB + col] = (bf16)u0[i];
                    sTmp2[(16 + l4 * 4 + i) * LDB + col] = (bf16)u1[i];
                }
            }
            // c1 GEMM: 4 col tiles per wave, K=512 via two A sources
            for (int nt = 0; nt < 4; ++nt) {
                size_t off = (size_t)(64 * w + nt * 16) * 512;
                Acc2 a = gtile(sL1, LDB, WbC1 + off, 512, 8, ZACC);
                a = gtile(sSeqB, LDB, WbC1 + off + 256, 512, 8, a);
                const int col = 64 * w + nt * 16 + l15;
                const float bi = b_c1[col];
#pragma unroll
                for (int i = 0; i < 4; ++i) {
                    sInter[(l4 * 4 + i) * LDI + col] = (bf16)gelu_f(a.a0[i] + bi);
                    sInter[(16 + l4 * 4 + i) * LDI + col] = (bf16)gelu_f(a.a1[i] + bi);
                }
            }
        }
        bar_lds();

        // ---- phase 4: conv over 5 slices + ts partials (atomic-free) ----
        {
            Acc2 av[2] = { ZACC, ZACC };
            const bf16* slices[5] = { sTmp, sL1, sSeqB, sR1, sTmp2 };
#pragma unroll 1
            for (int sl = 0; sl < 5; ++sl) {
                const bf16* Ab = slices[sl];
                av[0] = gtile(Ab, LDB, WbConv + (size_t)(n0) * 1280 + sl * 256, 1280, 8, av[0]);
                av[1] = gtile(Ab, LDB, WbConv + (size_t)(n0 + 16) * 1280 + sl * 256, 1280, 8, av[1]);
            }
#pragma unroll
            for (int mt = 0; mt < 2; ++mt)
#pragma unroll
                for (int i = 0; i < 4; ++i) {
                    int row = mt * 16 + l4 * 4 + i;
                    float p = 0.f;
#pragma unroll
                    for (int nt = 0; nt < 2; ++nt) {
                        int col = n0 + nt * 16 + l15;
                        float v = (mt == 0) ? av[nt].a0[i] : av[nt].a1[i];
                        float hv = gelu_f(v + b_conv[col]);
                        p += hv * W_sc[col];
                    }
                    p += __shfl_xor(p, 1); p += __shfl_xor(p, 2);
                    p += __shfl_xor(p, 4); p += __shfl_xor(p, 8);
                    if (l15 == 0) sTsP[row * 9 + w] = p;
                }
        }
        bar_lds();

        // ---- phase 5: tp ; c2 GEMM ; gates -> trans_pre ----
        if (tid < 32) {
            float t = b_sc[0];
            for (int ww = 0; ww < 8; ++ww) t += sTsP[tid * 9 + ww];
            sTp[tid] = sSelp[tid] * sigm_f(t);
        }
#pragma unroll 1
        for (int di = 0; di < 2; ++di) {
            const int dbase = (2 * w + di) * 16;
            Acc2 ag0 = gtile(sInter, LDI, WbC2 + (size_t)(0 * 256 + dbase) * 512, 512, 16, ZACC);
            Acc2 ag1 = gtile(sInter, LDI, WbC2 + (size_t)(1 * 256 + dbase) * 512, 512, 16, ZACC);
            Acc2 ag2 = gtile(sInter, LDI, WbC2 + (size_t)(2 * 256 + dbase) * 512, 512, 16, ZACC);
            Acc2 ag3 = gtile(sInter, LDI, WbC2 + (size_t)(3 * 256 + dbase) * 512, 512, 16, ZACC);
            const int d = dbase + l15;
            const float b0 = b_c2[d], b1 = b_c2[256 + d], b2 = b_c2[512 + d], b3 = b_c2[768 + d];
#pragma unroll
            for (int mt = 0; mt < 2; ++mt)
#pragma unroll
                for (int i = 0; i < 4; ++i) {
                    int row = mt * 16 + l4 * 4 + i;
                    float c0 = ((mt == 0) ? ag0.a0[i] : ag0.a1[i]) + b0;
                    float c1v = ((mt == 0) ? ag1.a0[i] : ag1.a1[i]) + b1;
                    float c2v = ((mt == 0) ? ag2.a0[i] : ag2.a1[i]) + b2;
                    float c3v = ((mt == 0) ? ag3.a0[i] : ag3.a1[i]) + b3;
                    float g0 = sigm_f(c0), g1 = sigm_f(c1v), g2 = sigm_f(c2v);
                    float lc = (float)sL1[row * LDB + d];
                    float sv = sSeq[row * 256 + d];
                    sTrans[row * 256 + d] = g0 * lc + g1 * sv + g2 * c3v;
                }
        }
        bar_lds();

        // ---- phase 6: trans = LN(trans_pre); seq update; active update ----
        {
            const int r = rg;
            float s = 0.f, s2 = 0.f, vals[16];
            for (int k = 0; k < 16; ++k) {
                float v = sTrans[r * 256 + q + 16 * k];
                vals[k] = v; s += v; s2 += v * v;
            }
            for (int m = 1; m < 16; m <<= 1) { s += __shfl_xor(s, m); s2 += __shfl_xor(s2, m); }
            float mu = s * (1.f / 256.f);
            float var = s2 * (1.f / 256.f) - mu * mu;
            float rstd = rsqrtf(var + 1e-5f);
            float tpv = sTp[r], imr = sIm[r];
            for (int k = 0; k < 16; ++k) {
                int c = q + 16 * k;
                float tr = (vals[k] - mu) * rstd * ln_g[c] + ln_b[c];
                float sv = sSeq[r * 256 + c];
                sSeq[r * 256 + c] = (tpv * tr + (1.f - tpv) * sv) * imr;
            }
        }
        if (tid < 32) {
            const int j = tid;
            float cons = 0.f;
            for (int i = 0; i < 32; ++i) cons += sLp[i * 32 + j] * sTp[i];
            sAct[j] = fmaxf(sAct[j] - cons, 0.f);
        }
        bar_lds();
    }

    // ---- output: sum_j ltm[j] * seq[j] ----
    if (tid < 256) {
        float o = 0.f;
        for (int j = 0; j < 32; ++j) o += sLtm[j] * sSeq[j * 256 + tid];
        out[(size_t)n * 256 + tid] = o;
    }
}

extern "C" void kernel_launch(void* const* d_in, const int* in_sizes, int n_in,
                              void* d_out, int out_size, void* d_ws, size_t ws_size,
                              hipStream_t stream) {
    const float* x       = (const float*)d_in[0];
    const float* inmask  = (const float*)d_in[1];
    const float* vSTART  = (const float*)d_in[2];
    const float* vEND    = (const float*)d_in[3];
    const float* W_init  = (const float*)d_in[4];
    const float* b_init  = (const float*)d_in[5];
    const float* ln_g    = (const float*)d_in[6];
    const float* ln_b    = (const float*)d_in[7];
    const float* W_conv  = (const float*)d_in[8];
    const float* b_conv  = (const float*)d_in[9];
    const float* W_sc    = (const float*)d_in[10];
    const float* b_sc    = (const float*)d_in[11];
    const float* W_c1    = (const float*)d_in[12];
    const float* b_c1    = (const float*)d_in[13];
    const float* W_c2    = (const float*)d_in[14];
    const float* b_c2    = (const float*)d_in[15];
    float* out = (float*)d_out;

    bf16* WbInit = (bf16*)d_ws;                 // 256 x 256
    bf16* WbConv = WbInit + 256 * 256;          // 256 x 1280
    bf16* WbC1   = WbConv + 256 * 1280;         // 512 x 512
    bf16* WbC2   = WbC1 + 512 * 512;            // 1024 x 512

    dim3 tb(32, 8);
    transpose_bf16_kernel<<<dim3(256 / 32, 256 / 32), tb, 0, stream>>>(W_init, WbInit, 256, 256);
    transpose_bf16_kernel<<<dim3(1280 / 32, 256 / 32), tb, 0, stream>>>(W_conv, WbConv, 1280, 256);
    transpose_bf16_kernel<<<dim3(512 / 32, 512 / 32), tb, 0, stream>>>(W_c1, WbC1, 512, 512);
    transpose_bf16_kernel<<<dim3(512 / 32, 1024 / 32), tb, 0, stream>>>(W_c2, WbC2, 512, 1024);

    (void)hipFuncSetAttribute((const void*)crvnn_main,
                              hipFuncAttributeMaxDynamicSharedMemorySize, SMEM_BYTES);
    crvnn_main<<<dim3(16), dim3(512), SMEM_BYTES, stream>>>(
        x, inmask, vSTART, vEND, b_init, ln_g, ln_b, b_conv, W_sc, b_sc,
        b_c1, b_c2, WbInit, WbConv, WbC1, WbC2, out);
}

// Round 10
// 1377.936 us; speedup vs baseline: 2.9238x; 2.4054x over previous
//
#include <hip/hip_runtime.h>
#include <hip/hip_bf16.h>
#include <math.h>

// ------------------------------------------------------------------
// CRvNN forward on MI355X. Round 10: STRUCTURAL rewrite. Each scan
// step = 4 small kernels spread over 64-256 blocks (vs 16); state in
// global (L2-resident); kernel boundaries are the sync. Per-batch
// early-exit via rem[b] check at kernel entry. 126 launches total.
// ------------------------------------------------------------------

typedef __bf16 bf16;
typedef bf16  bf16x8 __attribute__((ext_vector_type(8)));
typedef float f32x4  __attribute__((ext_vector_type(4)));

#define MFMA16(a,b,c) __builtin_amdgcn_mfma_f32_16x16x32_bf16((a),(b),(c),0,0,0)

__device__ __forceinline__ float gelu_f(float v) {
    return 0.5f * v * (1.0f + erff(v * 0.70710678118654752f));
}
__device__ __forceinline__ float sigm_f(float v) {
    return 1.0f / (1.0f + expf(-v));
}

// serial neighbor-prob routine, lanes 0..31 (caller gates tid<32)
__device__ __forceinline__ void compute_probs(const float* sAct, const float* sIm, int i,
                                              bf16* LpB, bf16* RpB, float* lpF) {
    for (int j = 0; j < 32; ++j) {
        LpB[i * 32 + j] = (bf16)0.f; RpB[i * 32 + j] = (bf16)0.f; lpF[i * 32 + j] = 0.f;
    }
    float cc = 0.f;
    for (int j = i + 1; j < 32; ++j) {
        float am = sAct[j] * sIm[j];
        float cp = cc; cc += am;
        float v = (cc > 1.f) ? fmaxf(1.f - cp, 0.f) : am;
        v *= sIm[j];
        RpB[i * 32 + j] = (bf16)v;
    }
    cc = 0.f;
    for (int j = i - 1; j >= 0; --j) {
        float am = sAct[j] * sIm[j];
        float cp = cc; cc += am;
        float v = (cc > 1.f) ? fmaxf(1.f - cp, 0.f) : am;
        v *= sIm[j];
        LpB[i * 32 + j] = (bf16)v; lpF[i * 32 + j] = v;
    }
}

// f32 [K][N] -> bf16 [N][K] transpose (32x32 tiles)
__global__ void transpose_bf16_kernel(const float* __restrict__ src,
                                      bf16* __restrict__ dst, int K, int N) {
    __shared__ float t[32][33];
    const int k0 = blockIdx.x * 32, n0 = blockIdx.y * 32;
    const int tx = threadIdx.x, ty = threadIdx.y;
#pragma unroll
    for (int i = 0; i < 4; ++i) {
        int k = k0 + ty + i * 8;
        t[ty + i * 8][tx] = src[(size_t)k * N + n0 + tx];
    }
    __syncthreads();
#pragma unroll
    for (int i = 0; i < 4; ++i) {
        int nn = n0 + ty + i * 8;
        dst[(size_t)nn * K + k0 + tx] = (bf16)t[tx][ty + i * 8];
    }
}

// ---- P1: masks, seq_pre, init GEMM + LN, initial probs ----
__global__ __launch_bounds__(256)
void p1_init(const float* __restrict__ x, const float* __restrict__ inmask,
             const float* __restrict__ vSTART, const float* __restrict__ vEND,
             const bf16* __restrict__ WbInit, const float* __restrict__ b_init,
             const float* __restrict__ ln_g, const float* __restrict__ ln_b,
             float* __restrict__ seqF, bf16* __restrict__ seqB,
             float* __restrict__ gIm, float* __restrict__ gSelp, float* __restrict__ gLtm,
             float* __restrict__ gAct, bf16* __restrict__ LpB, bf16* __restrict__ RpB,
             float* __restrict__ lpF, float* __restrict__ gRem) {
    const int b = blockIdx.x;
    const int tid = threadIdx.x;
    const int lane = tid & 63, w = tid >> 6, l15 = lane & 15, l4 = lane >> 4;
    __shared__ bf16 pre[32][264];
    __shared__ float fseq[32][256];
    __shared__ float sIm[32], sEndm[32], sSelp[32];
    const f32x4 ZERO = {0.f, 0.f, 0.f, 0.f};

    if (tid < 32) {
        const int r = tid;
        auto IM31 = [&](int j) -> float { return (j <= 0) ? 1.f : inmask[b * 30 + (j - 1)]; };
        float im_ye = (r == 0) ? 1.f : IM31(r - 1);
        float im_ne = (r <= 30) ? IM31(r) : 0.f;
        float endm  = im_ye - im_ne;
        float ins   = (r == 0) ? 0.f : im_ye;
        float ltm   = (r < 31) ? (IM31(r) - ((r <= 29) ? IM31(r + 1) : 0.f)) : 0.f;
        float selp  = ins * im_ne * (1.f - ltm);
        sIm[r] = im_ye; sEndm[r] = endm; sSelp[r] = selp;
        gIm[b * 32 + r] = im_ye; gSelp[b * 32 + r] = selp; gLtm[b * 32 + r] = ltm;
        gAct[b * 32 + r] = im_ye;
    }
    __syncthreads();
    {   // seq_pre: 256 thr, row = tid>>3, 32 cols each
        const int r = tid >> 3, s = tid & 7;
        const float em = sEndm[r];
        for (int k = 0; k < 4; ++k) {
            int c = s + 8 * (k * 8);  // strided; simple
            // do 32 elems: c = s + 8*kk for kk 0..31
        }
        for (int kk = 0; kk < 32; ++kk) {
            int c = s + 8 * kk;
            float base = (r == 0) ? vSTART[c] : ((r <= 30) ? x[(size_t)(b * 30 + (r - 1)) * 256 + c] : 0.f);
            pre[r][c] = (bf16)(em * vEND[c] + (1.f - em) * base);
        }
    }
    __syncthreads();
    // init GEMM: 4 waves x 4 ntiles of 16 cols
    for (int nt = 0; nt < 4; ++nt) {
        const int col0 = w * 64 + nt * 16;
        f32x4 a0 = ZERO, a1 = ZERO;
        const bf16* Wp = WbInit + (size_t)(col0 + l15) * 256 + l4 * 8;
#pragma unroll
        for (int kt = 0; kt < 8; ++kt) {
            int kk = kt * 32 + l4 * 8;
            bf16x8 bfr = *(const bf16x8*)(Wp + kt * 32);
            bf16x8 af0 = *(const bf16x8*)(&pre[l15][kk]);
            bf16x8 af1 = *(const bf16x8*)(&pre[16 + l15][kk]);
            a0 = MFMA16(af0, bfr, a0);
            a1 = MFMA16(af1, bfr, a1);
        }
        const int col = col0 + l15;
        const float bi = b_init[col];
#pragma unroll
        for (int i = 0; i < 4; ++i) {
            fseq[l4 * 4 + i][col] = a0[i] + bi;
            fseq[16 + l4 * 4 + i][col] = a1[i] + bi;
        }
    }
    __syncthreads();
    {   // LN rows (8 thr/row) * im -> seqF, seqB
        const int r = tid >> 3, s = tid & 7;
        float vals[32], sm = 0.f, s2 = 0.f;
        for (int k = 0; k < 32; ++k) {
            float v = fseq[r][s + 8 * k];
            vals[k] = v; sm += v; s2 += v * v;
        }
        for (int m = 1; m < 8; m <<= 1) { sm += __shfl_xor(sm, m); s2 += __shfl_xor(s2, m); }
        float mu = sm * (1.f / 256.f);
        float var = s2 * (1.f / 256.f) - mu * mu;
        float rstd = rsqrtf(var + 1e-5f);
        float imr = sIm[r];
        for (int k = 0; k < 32; ++k) {
            int c = s + 8 * k;
            float v = ((vals[k] - mu) * rstd * ln_g[c] + ln_b[c]) * imr;
            seqF[((size_t)b * 32 + r) * 256 + c] = v;
            seqB[((size_t)b * 32 + r) * 256 + c] = (bf16)v;
        }
    }
    __syncthreads();
    if (tid < 32) {
        compute_probs(sIm /*act==im*/, sIm, tid,
                      LpB + (size_t)b * 1024, RpB + (size_t)b * 1024, lpF + (size_t)b * 1024);
        if (tid == 0) {
            float rm = 0.f;
            for (int j = 0; j < 32; ++j) rm += sIm[j] * sSelp[j];
            gRem[b] = rm;
        }
    }
}

// ---- K1: L1 = Lp@seq, R1 = Rp@seq, L2 = Lp@L1, R2 = Rp@R1 (col-local) ----
__global__ __launch_bounds__(256)
void k1_neighbors(const bf16* __restrict__ seqB, const bf16* __restrict__ LpB,
                  const bf16* __restrict__ RpB, const float* __restrict__ gRem,
                  bf16* __restrict__ L1, bf16* __restrict__ R1,
                  bf16* __restrict__ L2, bf16* __restrict__ R2) {
    const int b = blockIdx.x >> 2, ct = blockIdx.x & 3;
    if (gRem[b] <= 0.01f) return;
    const int tid = threadIdx.x;
    const int lane = tid & 63, w = tid >> 6, l15 = lane & 15, l4 = lane >> 4;
    const int c0 = ct * 64;
    __shared__ bf16 tS[32][72], tL[32][72], tR[32][72];
    const f32x4 ZERO = {0.f, 0.f, 0.f, 0.f};

    {   // stage seq col-tile
        const int r = tid >> 3, cc = (tid & 7) * 8;
        *(bf16x8*)&tS[r][cc] = *(const bf16x8*)(seqB + ((size_t)b * 32 + r) * 256 + c0 + cc);
    }
    const bf16* lp = LpB + (size_t)b * 1024;
    const bf16* rp = RpB + (size_t)b * 1024;
    bf16x8 aL0 = *(const bf16x8*)(lp + l15 * 32 + l4 * 8);
    bf16x8 aL1 = *(const bf16x8*)(lp + (16 + l15) * 32 + l4 * 8);
    bf16x8 aR0 = *(const bf16x8*)(rp + l15 * 32 + l4 * 8);
    bf16x8 aR1 = *(const bf16x8*)(rp + (16 + l15) * 32 + l4 * 8);
    __syncthreads();

    const int cl = w * 16 + l15;            // col within tile
    const int col = c0 + cl;                // global col
    {
        bf16x8 bx;
#pragma unroll
        for (int s2 = 0; s2 < 8; ++s2) bx[s2] = tS[l4 * 8 + s2][cl];
        f32x4 vL0 = MFMA16(aL0, bx, ZERO);
        f32x4 vL1 = MFMA16(aL1, bx, ZERO);
        f32x4 vR0 = MFMA16(aR0, bx, ZERO);
        f32x4 vR1 = MFMA16(aR1, bx, ZERO);
#pragma unroll
        for (int i = 0; i < 4; ++i) {
            int r0 = l4 * 4 + i, r1 = 16 + l4 * 4 + i;
            tL[r0][cl] = (bf16)vL0[i]; tL[r1][cl] = (bf16)vL1[i];
            tR[r0][cl] = (bf16)vR0[i]; tR[r1][cl] = (bf16)vR1[i];
            L1[((size_t)b * 32 + r0) * 256 + col] = (bf16)vL0[i];
            L1[((size_t)b * 32 + r1) * 256 + col] = (bf16)vL1[i];
            R1[((size_t)b * 32 + r0) * 256 + col] = (bf16)vR0[i];
            R1[((size_t)b * 32 + r1) * 256 + col] = (bf16)vR1[i];
        }
    }
    __syncthreads();
    {
        bf16x8 bxL, bxR;
#pragma unroll
        for (int s2 = 0; s2 < 8; ++s2) {
            bxL[s2] = tL[l4 * 8 + s2][cl];
            bxR[s2] = tR[l4 * 8 + s2][cl];
        }
        f32x4 vL0 = MFMA16(aL0, bxL, ZERO);
        f32x4 vL1 = MFMA16(aL1, bxL, ZERO);
        f32x4 vR0 = MFMA16(aR0, bxR, ZERO);
        f32x4 vR1 = MFMA16(aR1, bxR, ZERO);
#pragma unroll
        for (int i = 0; i < 4; ++i) {
            int r0 = l4 * 4 + i, r1 = 16 + l4 * 4 + i;
            L2[((size_t)b * 32 + r0) * 256 + col] = (bf16)vL0[i];
            L2[((size_t)b * 32 + r1) * 256 + col] = (bf16)vL1[i];
            R2[((size_t)b * 32 + r0) * 256 + col] = (bf16)vR0[i];
            R2[((size_t)b * 32 + r1) * 256 + col] = (bf16)vR1[i];
        }
    }
}

// ---- K2: c1 (roles 0..7) and conv+ts (roles 8..11) ----
__global__ __launch_bounds__(256)
void k2_c1_conv(const bf16* __restrict__ L1, const bf16* __restrict__ seqB,
                const bf16* __restrict__ L2, const bf16* __restrict__ R1,
                const bf16* __restrict__ R2, const bf16* __restrict__ WbC1,
                const bf16* __restrict__ WbConv, const float* __restrict__ b_c1,
                const float* __restrict__ b_conv, const float* __restrict__ W_sc,
                const float* __restrict__ gRem, bf16* __restrict__ inter,
                float* __restrict__ tsPart) {
    const int b = blockIdx.x / 12, role = blockIdx.x % 12;
    if (gRem[b] <= 0.01f) return;
    const int tid = threadIdx.x;
    const int lane = tid & 63, w = tid >> 6, l15 = lane & 15, l4 = lane >> 4;
    const f32x4 ZERO = {0.f, 0.f, 0.f, 0.f};
    const size_t bs = (size_t)b * 32 * 256;

    if (role < 8) {
        const int col0 = role * 64 + w * 16;
        f32x4 a0 = ZERO, a1 = ZERO;
        const bf16* A1 = L1 + bs;
        const bf16* A2 = seqB + bs;
        const bf16* Wp = WbC1 + (size_t)(col0 + l15) * 512 + l4 * 8;
#pragma unroll
        for (int kt = 0; kt < 16; ++kt) {
            const bf16* As = (kt < 8) ? A1 : A2;
            int kk = (kt & 7) * 32 + l4 * 8;
            bf16x8 bfr = *(const bf16x8*)(Wp + kt * 32);
            bf16x8 af0 = *(const bf16x8*)(As + l15 * 256 + kk);
            bf16x8 af1 = *(const bf16x8*)(As + (16 + l15) * 256 + kk);
            a0 = MFMA16(af0, bfr, a0);
            a1 = MFMA16(af1, bfr, a1);
        }
        const int col = col0 + l15;
        const float bi = b_c1[col];
#pragma unroll
        for (int i = 0; i < 4; ++i) {
            inter[((size_t)b * 32 + l4 * 4 + i) * 512 + col] = (bf16)gelu_f(a0[i] + bi);
            inter[((size_t)b * 32 + 16 + l4 * 4 + i) * 512 + col] = (bf16)gelu_f(a1[i] + bi);
        }
    } else {
        const int j = role - 8;
        const int col0 = j * 64 + w * 16;
        f32x4 a0 = ZERO, a1 = ZERO;
        const bf16* slices[5] = { L2 + bs, L1 + bs, seqB + bs, R1 + bs, R2 + bs };
        const bf16* Wp = WbConv + (size_t)(col0 + l15) * 1280 + l4 * 8;
#pragma unroll
        for (int sl = 0; sl < 5; ++sl) {
            const bf16* As = slices[sl];
#pragma unroll
            for (int kt = 0; kt < 8; ++kt) {
                int kk = kt * 32 + l4 * 8;
                bf16x8 bfr = *(const bf16x8*)(Wp + sl * 256 + kt * 32);
                bf16x8 af0 = *(const bf16x8*)(As + l15 * 256 + kk);
                bf16x8 af1 = *(const bf16x8*)(As + (16 + l15) * 256 + kk);
                a0 = MFMA16(af0, bfr, a0);
                a1 = MFMA16(af1, bfr, a1);
            }
        }
        __shared__ float red[4][32];
        const int col = col0 + l15;
        const float bc = b_conv[col], ws = W_sc[col];
#pragma unroll
        for (int mt = 0; mt < 2; ++mt)
#pragma unroll
            for (int i = 0; i < 4; ++i) {
                int row = mt * 16 + l4 * 4 + i;
                float p = gelu_f(((mt == 0) ? a0[i] : a1[i]) + bc) * ws;
                p += __shfl_xor(p, 1); p += __shfl_xor(p, 2);
                p += __shfl_xor(p, 4); p += __shfl_xor(p, 8);
                if (l15 == 0) red[w][row] = p;
            }
        __syncthreads();
        if (tid < 32)
            tsPart[((size_t)b * 4 + j) * 32 + tid] =
                red[0][tid] + red[1][tid] + red[2][tid] + red[3][tid];
    }
}

// ---- K3: c2 + gates -> transPre ----
__global__ __launch_bounds__(256)
void k3_c2(const bf16* __restrict__ inter, const bf16* __restrict__ WbC2,
           const float* __restrict__ b_c2, const bf16* __restrict__ L1,
           const float* __restrict__ seqF, const float* __restrict__ gRem,
           float* __restrict__ transPre) {
    const int b = blockIdx.x >> 4, dt = blockIdx.x & 15;
    if (gRem[b] <= 0.01f) return;
    const int tid = threadIdx.x;
    const int lane = tid & 63, w = tid >> 6, l15 = lane & 15, l4 = lane >> 4;
    const f32x4 ZERO = {0.f, 0.f, 0.f, 0.f};
    const int col0 = w * 256 + dt * 16;   // gate w, d-block dt
    f32x4 a0 = ZERO, a1 = ZERO;
    const bf16* A = inter + (size_t)b * 32 * 512;
    const bf16* Wp = WbC2 + (size_t)(col0 + l15) * 512 + l4 * 8;
#pragma unroll
    for (int kt = 0; kt < 16; ++kt) {
        int kk = kt * 32 + l4 * 8;
        bf16x8 bfr = *(const bf16x8*)(Wp + kt * 32);
        bf16x8 af0 = *(const bf16x8*)(A + l15 * 512 + kk);
        bf16x8 af1 = *(const bf16x8*)(A + (16 + l15) * 512 + kk);
        a0 = MFMA16(af0, bfr, a0);
        a1 = MFMA16(af1, bfr, a1);
    }
    __shared__ float g[4][32][16];
    const float bc = b_c2[col0 + l15];
#pragma unroll
    for (int i = 0; i < 4; ++i) {
        g[w][l4 * 4 + i][l15] = a0[i] + bc;
        g[w][16 + l4 * 4 + i][l15] = a1[i] + bc;
    }
    __syncthreads();
    for (int t = tid; t < 512; t += 256) {
        int row = t >> 4, dd = t & 15, d = dt * 16 + dd;
        float g0 = sigm_f(g[0][row][dd]);
        float g1 = sigm_f(g[1][row][dd]);
        float g2 = sigm_f(g[2][row][dd]);
        float c3v = g[3][row][dd];
        float lc = (float)L1[((size_t)b * 32 + row) * 256 + d];
        float sv = seqF[((size_t)b * 32 + row) * 256 + d];
        transPre[((size_t)b * 32 + row) * 256 + d] = g0 * lc + g1 * sv + g2 * c3v;
    }
}

// ---- K4: ts->tp, LN+blend, act update, probs for next step ----
__global__ __launch_bounds__(256)
void k4_final(const float* __restrict__ transPre, const float* __restrict__ tsPart,
              const float* __restrict__ b_sc, const float* __restrict__ ln_g,
              const float* __restrict__ ln_b, const float* __restrict__ gIm,
              const float* __restrict__ gSelp, float* __restrict__ lpF,
              float* __restrict__ gRem, float* __restrict__ gAct,
              float* __restrict__ seqF, bf16* __restrict__ seqB,
              bf16* __restrict__ LpB, bf16* __restrict__ RpB) {
    const int b = blockIdx.x;
    if (gRem[b] <= 0.01f) return;
    const int tid = threadIdx.x;
    __shared__ float sTp[32], sAct[32], sIm[32], sSelp[32];
    if (tid < 32) {
        float t = b_sc[0];
#pragma unroll
        for (int p = 0; p < 4; ++p) t += tsPart[((size_t)b * 4 + p) * 32 + tid];
        sIm[tid] = gIm[b * 32 + tid];
        sSelp[tid] = gSelp[b * 32 + tid];
        sTp[tid] = sSelp[tid] * sigm_f(t);
    }
    __syncthreads();
    {   // LN + blend (8 thr/row)
        const int r = tid >> 3, s = tid & 7;
        float vals[32], sm = 0.f, s2 = 0.f;
        for (int k = 0; k < 32; ++k) {
            float v = transPre[((size_t)b * 32 + r) * 256 + s + 8 * k];
            vals[k] = v; sm += v; s2 += v * v;
        }
        for (int m = 1; m < 8; m <<= 1) { sm += __shfl_xor(sm, m); s2 += __shfl_xor(s2, m); }
        float mu = sm * (1.f / 256.f);
        float var = s2 * (1.f / 256.f) - mu * mu;
        float rstd = rsqrtf(var + 1e-5f);
        float tp = sTp[r], imr = sIm[r];
        for (int k = 0; k < 32; ++k) {
            int c = s + 8 * k;
            float tr = (vals[k] - mu) * rstd * ln_g[c] + ln_b[c];
            float sv = seqF[((size_t)b * 32 + r) * 256 + c];
            float ns = (tp * tr + (1.f - tp) * sv) * imr;
            seqF[((size_t)b * 32 + r) * 256 + c] = ns;
            seqB[((size_t)b * 32 + r) * 256 + c] = (bf16)ns;
        }
    }
    if (tid < 32) {
        float cons = 0.f;
        for (int i = 0; i < 32; ++i) cons += lpF[((size_t)b * 32 + i) * 32 + tid] * sTp[i];
        float a = fmaxf(gAct[b * 32 + tid] - cons, 0.f);
        gAct[b * 32 + tid] = a;
        sAct[tid] = a;
    }
    __syncthreads();
    if (tid < 32) {
        compute_probs(sAct, sIm, tid,
                      LpB + (size_t)b * 1024, RpB + (size_t)b * 1024, lpF + (size_t)b * 1024);
        if (tid == 0) {
            float rm = 0.f;
            for (int j = 0; j < 32; ++j) rm += sAct[j] * sSelp[j];
            gRem[b] = rm;
        }
    }
}

// ---- KOut ----
__global__ __launch_bounds__(256)
void kout(const float* __restrict__ seqF, const float* __restrict__ gLtm,
          float* __restrict__ out) {
    const int b = blockIdx.x, d = threadIdx.x;
    float o = 0.f;
    for (int j = 0; j < 32; ++j) o += gLtm[b * 32 + j] * seqF[((size_t)b * 32 + j) * 256 + d];
    out[(size_t)b * 256 + d] = o;
}

extern "C" void kernel_launch(void* const* d_in, const int* in_sizes, int n_in,
                              void* d_out, int out_size, void* d_ws, size_t ws_size,
                              hipStream_t stream) {
    const float* x       = (const float*)d_in[0];
    const float* inmask  = (const float*)d_in[1];
    const float* vSTART  = (const float*)d_in[2];
    const float* vEND    = (const float*)d_in[3];
    const float* W_init  = (const float*)d_in[4];
    const float* b_init  = (const float*)d_in[5];
    const float* ln_g    = (const float*)d_in[6];
    const float* ln_b    = (const float*)d_in[7];
    const float* W_conv  = (const float*)d_in[8];
    const float* b_conv  = (const float*)d_in[9];
    const float* W_sc    = (const float*)d_in[10];
    const float* b_sc    = (const float*)d_in[11];
    const float* W_c1    = (const float*)d_in[12];
    const float* b_c1    = (const float*)d_in[13];
    const float* W_c2    = (const float*)d_in[14];
    const float* b_c2    = (const float*)d_in[15];
    float* out = (float*)d_out;

    // ---- workspace layout ----
    char* p = (char*)d_ws;
    auto alloc = [&](size_t bytes) { char* r = p; p += (bytes + 255) & ~(size_t)255; return r; };
    bf16*  WbInit  = (bf16*)alloc(256 * 256 * 2);
    bf16*  WbConv  = (bf16*)alloc(256 * 1280 * 2);
    bf16*  WbC1    = (bf16*)alloc(512 * 512 * 2);
    bf16*  WbC2    = (bf16*)alloc(1024 * 512 * 2);
    float* seqF    = (float*)alloc(16 * 32 * 256 * 4);
    float* transPre= (float*)alloc(16 * 32 * 256 * 4);
    bf16*  seqB    = (bf16*)alloc(16 * 32 * 256 * 2);
    bf16*  L1      = (bf16*)alloc(16 * 32 * 256 * 2);
    bf16*  R1      = (bf16*)alloc(16 * 32 * 256 * 2);
    bf16*  L2      = (bf16*)alloc(16 * 32 * 256 * 2);
    bf16*  R2      = (bf16*)alloc(16 * 32 * 256 * 2);
    bf16*  inter   = (bf16*)alloc(16 * 32 * 512 * 2);
    bf16*  LpB     = (bf16*)alloc(16 * 32 * 32 * 2);
    bf16*  RpB     = (bf16*)alloc(16 * 32 * 32 * 2);
    float* lpF     = (float*)alloc(16 * 32 * 32 * 4);
    float* tsPart  = (float*)alloc(16 * 4 * 32 * 4);
    float* gAct    = (float*)alloc(16 * 32 * 4);
    float* gIm     = (float*)alloc(16 * 32 * 4);
    float* gSelp   = (float*)alloc(16 * 32 * 4);
    float* gLtm    = (float*)alloc(16 * 32 * 4);
    float* gRem    = (float*)alloc(16 * 4);

    dim3 tb(32, 8);
    transpose_bf16_kernel<<<dim3(256 / 32, 256 / 32), tb, 0, stream>>>(W_init, WbInit, 256, 256);
    transpose_bf16_kernel<<<dim3(1280 / 32, 256 / 32), tb, 0, stream>>>(W_conv, WbConv, 1280, 256);
    transpose_bf16_kernel<<<dim3(512 / 32, 512 / 32), tb, 0, stream>>>(W_c1, WbC1, 512, 512);
    transpose_bf16_kernel<<<dim3(512 / 32, 1024 / 32), tb, 0, stream>>>(W_c2, WbC2, 512, 1024);

    p1_init<<<16, 256, 0, stream>>>(x, inmask, vSTART, vEND, WbInit, b_init, ln_g, ln_b,
                                    seqF, seqB, gIm, gSelp, gLtm, gAct, LpB, RpB, lpF, gRem);

    for (int step = 0; step < 30; ++step) {
        k1_neighbors<<<64, 256, 0, stream>>>(seqB, LpB, RpB, gRem, L1, R1, L2, R2);
        k2_c1_conv<<<192, 256, 0, stream>>>(L1, seqB, L2, R1, R2, WbC1, WbConv,
                                            b_c1, b_conv, W_sc, gRem, inter, tsPart);
        k3_c2<<<256, 256, 0, stream>>>(inter, WbC2, b_c2, L1, seqF, gRem, transPre);
        k4_final<<<16, 256, 0, stream>>>(transPre, tsPart, b_sc, ln_g, ln_b, gIm, gSelp,
                                         lpF, gRem, gAct, seqF, seqB, LpB, RpB);
    }
    kout<<<16, 256, 0, stream>>>(seqF, gLtm, out);
}